// Round 1
// baseline (6128.208 us; speedup 1.0000x reference)
//
#include <hip/hip_runtime.h>
#include <math.h>

typedef _Float16 half_t;
typedef _Float16 half8 __attribute__((ext_vector_type(8)));
typedef float f32x4 __attribute__((ext_vector_type(4)));

#define B_ 128
#define T_ 256
#define I_ 512
#define H_ 1024

// ---------------------------------------------------------------------------
// prep: convert x fp32 -> fp16 (8 elems/thread)
__global__ void k_convert_x(const float* __restrict__ x, half_t* __restrict__ x16, int n8) {
    int i = blockIdx.x * blockDim.x + threadIdx.x;
    if (i >= n8) return;
    const float4* xv = (const float4*)x;
    float4 a = xv[2 * i], b = xv[2 * i + 1];
    half8 o;
    o[0] = (half_t)a.x; o[1] = (half_t)a.y; o[2] = (half_t)a.z; o[3] = (half_t)a.w;
    o[4] = (half_t)b.x; o[5] = (half_t)b.y; o[6] = (half_t)b.z; o[7] = (half_t)b.w;
    ((half8*)x16)[i] = o;
}

// prep: pack W_ih|W_hh (fp32, torch gate order i,f,g,o) into fp16 MFMA
// B-fragment order. Layout: [hgroup(128)][kb(Ktot/32)][ntile(2)][lane(64)][j(8)]
// B-frag (16x16x32): lane l holds B[k=(l>>4)*8+j][n=l&15]; n local col c = nt*16+(l&15),
// c = gate*8+hoff -> original row = gate*1024 + hg*8 + hoff.
__global__ void k_pack_w(const float* __restrict__ Wih, const float* __restrict__ Whh,
                         half_t* __restrict__ out, int Kx, int Ktot) {
    int idx = blockIdx.x * blockDim.x + threadIdx.x;
    int total = 4096 * Ktot;
    if (idx >= total) return;
    int j = idx & 7;
    int lane = (idx >> 3) & 63;
    int nt = (idx >> 9) & 1;
    int rest = idx >> 10;
    int nkb = Ktot >> 5;
    int kb = rest % nkb;
    int hg = rest / nkb;
    int nl = nt * 16 + (lane & 15);
    int gate = nl >> 3, hoff = nl & 7;
    int row = gate * 1024 + hg * 8 + hoff;
    int k = kb * 32 + (lane >> 4) * 8 + j;
    float v = (k < Kx) ? Wih[(size_t)row * Kx + k] : Whh[(size_t)row * 1024 + (k - Kx)];
    out[idx] = (half_t)v;
}

// prep: bias packed to [hgroup*32 + gate*8 + hoff], b_ih + b_hh summed
__global__ void k_pack_bias(const float* __restrict__ bih, const float* __restrict__ bhh,
                            float* __restrict__ out) {
    int idx = blockIdx.x * blockDim.x + threadIdx.x;
    if (idx >= 4096) return;
    int hg = idx >> 5, c = idx & 31;
    int gate = c >> 3, hoff = c & 7;
    int row = gate * 1024 + hg * 8 + hoff;
    out[idx] = bih[row] + bhh[row];
}

__global__ void k_zero(unsigned int* __restrict__ p, int n) {
    int i = blockIdx.x * blockDim.x + threadIdx.x;
    if (i < n) p[i] = 0u;
}

// ---------------------------------------------------------------------------
// One LSTM timestep: gates = [x_t | h_prev] @ Wpack^T + bias, then elementwise.
// Grid 256 = 128 hgroups x 2 mgroups. Block 1024 = 16 waves: w = kh*2+mh.
// WG tile: rows m0..m0+63, cols = hgroup's 8 h-indices x 4 gates (32).
// Wave: [32 rows x 32 cols] over K/8 slice; fp32 partials reduced via LDS.
template <int KX>
__launch_bounds__(1024)
__global__ void lstm_step(const half_t* __restrict__ Ax, const half_t* __restrict__ hprev,
                          const half_t* __restrict__ Wp, const float* __restrict__ biasp,
                          float* __restrict__ cst, half_t* __restrict__ hnext,
                          half_t* __restrict__ hseq, int t, int write_seq) {
    constexpr int KTOT = KX + 1024;
    constexpr int NKB = KTOT >> 5;     // 48 (L0) / 64 (L1)
    constexpr int KB_PER = NKB >> 3;   // 6 / 8 per kh-wave

    __shared__ float gacc[8 * 64 * 32];  // 64 KB: [kh][m(64)][n(32)], n XOR-swizzled

    int bid = blockIdx.x;
    int hg = bid & 127, mg = bid >> 7;
    int m0 = mg * 64;
    int tid = threadIdx.x;
    int w = tid >> 6, lane = tid & 63;
    int mh = w & 1, kh = w >> 1;
    int q = lane >> 4, ml = lane & 15;

    f32x4 acc00 = (f32x4)0.f, acc01 = (f32x4)0.f, acc10 = (f32x4)0.f, acc11 = (f32x4)0.f;

    int rowA0 = m0 + mh * 32 + ml;
    int rowA1 = rowA0 + 16;
    const size_t xrow0 = ((size_t)rowA0 * T_ + t) * KX;
    const size_t xrow1 = ((size_t)rowA1 * T_ + t) * KX;
    const size_t hrow0 = (size_t)rowA0 * H_;
    const size_t hrow1 = (size_t)rowA1 * H_;

    const half8* Wp8 = (const half8*)Wp;
    const size_t wbase = (size_t)hg * NKB * 128;  // half8 units

    int kb0 = kh * KB_PER;
#pragma unroll
    for (int ib = 0; ib < KB_PER; ib++) {
        int kb = kb0 + ib;
        int kg = kb * 32 + q * 8;
        half8 a0, a1;
        if (kg < KX) {
            a0 = *(const half8*)(Ax + xrow0 + kg);
            a1 = *(const half8*)(Ax + xrow1 + kg);
        } else {
            a0 = *(const half8*)(hprev + hrow0 + (kg - KX));
            a1 = *(const half8*)(hprev + hrow1 + (kg - KX));
        }
        half8 b0 = Wp8[wbase + (size_t)kb * 128 + lane];
        half8 b1 = Wp8[wbase + (size_t)kb * 128 + 64 + lane];
        acc00 = __builtin_amdgcn_mfma_f32_16x16x32_f16(a0, b0, acc00, 0, 0, 0);
        acc01 = __builtin_amdgcn_mfma_f32_16x16x32_f16(a0, b1, acc01, 0, 0, 0);
        acc10 = __builtin_amdgcn_mfma_f32_16x16x32_f16(a1, b0, acc10, 0, 0, 0);
        acc11 = __builtin_amdgcn_mfma_f32_16x16x32_f16(a1, b1, acc11, 0, 0, 0);
    }

    // store partials: C/D layout col=lane&15, row=(lane>>4)*4+r  (m89-verified)
#pragma unroll
    for (int mi = 0; mi < 2; mi++) {
#pragma unroll
        for (int ni = 0; ni < 2; ni++) {
            const f32x4& a = mi == 0 ? (ni == 0 ? acc00 : acc01) : (ni == 0 ? acc10 : acc11);
#pragma unroll
            for (int r = 0; r < 4; r++) {
                int m_l = mh * 32 + mi * 16 + q * 4 + r;
                int n_l = ni * 16 + ml;
                int n_s = n_l ^ ((m_l & 3) << 3);  // bank-conflict swizzle
                gacc[(kh * 64 + m_l) * 32 + n_s] = a[r];
            }
        }
    }
    __syncthreads();

    if (tid < 512) {
        int m_l = tid >> 3, hoff = tid & 7;
        int sw = (m_l & 3) << 3;
        float pi = 0.f, pf = 0.f, pg = 0.f, po = 0.f;
#pragma unroll
        for (int z = 0; z < 8; z++) {
            const float* g = &gacc[(z * 64 + m_l) * 32];
            pi += g[(0 + hoff) ^ sw];
            pf += g[(8 + hoff) ^ sw];
            pg += g[(16 + hoff) ^ sw];
            po += g[(24 + hoff) ^ sw];
        }
        int bb = hg * 32;
        pi += biasp[bb + hoff];
        pf += biasp[bb + 8 + hoff];
        pg += biasp[bb + 16 + hoff];
        po += biasp[bb + 24 + hoff];
        int mgl = m0 + m_l;
        int hidx = hg * 8 + hoff;
        float cold = cst[mgl * H_ + hidx];
        float si = 1.f / (1.f + __expf(-pi));
        float sf = 1.f / (1.f + __expf(-pf));
        float so = 1.f / (1.f + __expf(-po));
        float tg = 1.f - 2.f / (__expf(2.f * pg) + 1.f);
        float cn = sf * cold + si * tg;
        float th = 1.f - 2.f / (__expf(2.f * cn) + 1.f);
        float hn = so * th;
        cst[mgl * H_ + hidx] = cn;
        hnext[mgl * H_ + hidx] = (half_t)hn;
        if (write_seq) hseq[((size_t)mgl * T_ + t) * H_ + hidx] = (half_t)hn;
    }
}

// final FC: out[m] = sum_k h[m][k] * Wfc[k] + bfc  (NC=1)
__global__ void k_fc(const half_t* __restrict__ h, const float* __restrict__ Wfc,
                     const float* __restrict__ bfc, float* __restrict__ out) {
    int m = blockIdx.x, lane = threadIdx.x;
    float s = 0.f;
    for (int k = lane; k < H_; k += 64) s += (float)h[m * H_ + k] * Wfc[k];
#pragma unroll
    for (int o = 32; o; o >>= 1) s += __shfl_down(s, o, 64);
    if (lane == 0) out[m] = s + bfc[0];
}

// ---------------------------------------------------------------------------
extern "C" void kernel_launch(void* const* d_in, const int* in_sizes, int n_in,
                              void* d_out, int out_size, void* d_ws, size_t ws_size,
                              hipStream_t stream) {
    const float* x    = (const float*)d_in[0];
    const float* Wih0 = (const float*)d_in[1];
    const float* Whh0 = (const float*)d_in[2];
    const float* bih0 = (const float*)d_in[3];
    const float* bhh0 = (const float*)d_in[4];
    const float* Wih1 = (const float*)d_in[5];
    const float* Whh1 = (const float*)d_in[6];
    const float* bih1 = (const float*)d_in[7];
    const float* bhh1 = (const float*)d_in[8];
    const float* Wfc  = (const float*)d_in[9];
    const float* bfc  = (const float*)d_in[10];
    float* out = (float*)d_out;

    char* ws = (char*)d_ws;
    size_t off = 0;
    auto carve = [&](size_t bytes) { void* p = ws + off; off += (bytes + 255) & ~(size_t)255; return p; };
    half_t* x16    = (half_t*)carve((size_t)B_ * T_ * I_ * 2);        // 33.5 MB
    half_t* h1_all = (half_t*)carve((size_t)B_ * T_ * H_ * 2);        // 67 MB
    half_t* wp0    = (half_t*)carve((size_t)4096 * 1536 * 2);         // 12.6 MB
    half_t* wp1    = (half_t*)carve((size_t)4096 * 2048 * 2);         // 16.8 MB
    float*  bias0  = (float*)carve(4096 * 4);
    float*  bias1  = (float*)carve(4096 * 4);
    char*   states = (char*)carve(4 * (size_t)B_ * H_ * 2 + 2 * (size_t)B_ * H_ * 4);  // 2 MB
    if (off > ws_size) return;  // ws too small: leave output untouched (visible failure)

    half_t* h0a = (half_t*)states;
    half_t* h0b = h0a + B_ * H_;
    half_t* h1a = h0b + B_ * H_;
    half_t* h1b = h1a + B_ * H_;
    float*  c0  = (float*)(h1b + B_ * H_);
    float*  c1  = c0 + B_ * H_;

    // prep
    k_convert_x<<<(B_ * T_ * I_ / 8 + 255) / 256, 256, 0, stream>>>(x, x16, B_ * T_ * I_ / 8);
    k_pack_w<<<(4096 * 1536 + 255) / 256, 256, 0, stream>>>(Wih0, Whh0, wp0, 512, 1536);
    k_pack_w<<<(4096 * 2048 + 255) / 256, 256, 0, stream>>>(Wih1, Whh1, wp1, 1024, 2048);
    k_pack_bias<<<16, 256, 0, stream>>>(bih0, bhh0, bias0);
    k_pack_bias<<<16, 256, 0, stream>>>(bih1, bhh1, bias1);
    k_zero<<<2048, 256, 0, stream>>>((unsigned int*)states, 524288);  // zero h bufs + c bufs (2 MB)

    half_t* hb0[2] = {h0a, h0b};
    half_t* hb1[2] = {h1a, h1b};
    for (int t = 0; t < T_; t++) {
        lstm_step<512><<<256, 1024, 0, stream>>>(x16, hb0[t & 1], wp0, bias0, c0,
                                                 hb0[(t + 1) & 1], h1_all, t, 1);
    }
    for (int t = 0; t < T_; t++) {
        lstm_step<1024><<<256, 1024, 0, stream>>>(h1_all, hb1[t & 1], wp1, bias1, c1,
                                                  hb1[(t + 1) & 1], h1_all, t, 0);
    }
    k_fc<<<128, 64, 0, stream>>>(hb1[0], Wfc, bfc, out);
}